// Round 1
// baseline (375.084 us; speedup 1.0000x reference)
//
#include <hip/hip_runtime.h>
#include <math.h>

#define NN 64      // nodes
#define TT 256     // frames
#define FF 13      // input features
#define EE 4032    // edges (complete digraph)
#define PP 128     // pooling channels / GAT1 out
#define HH 128     // hidden

__device__ __forceinline__ float wave_max64(float v) {
#pragma unroll
  for (int off = 32; off > 0; off >>= 1) v = fmaxf(v, __shfl_xor(v, off, 64));
  return v;
}
__device__ __forceinline__ float wave_sum64(float v) {
#pragma unroll
  for (int off = 32; off > 0; off >>= 1) v += __shfl_xor(v, off, 64);
  return v;
}
__device__ __forceinline__ float sigm(float x) { return 1.f / (1.f + __expf(-x)); }
__device__ __forceinline__ float tanh_fast(float x) { return 1.f - 2.f / (__expf(2.f * x) + 1.f); }

// ---------------------------------------------------------------------------
// Per-frame GNN: GAT1 (4 heads) -> relu -> GAT2 (1 head) -> relu ->
// attention-pool + max-pool -> embs[t][256]
// One block per frame, 512 threads (8 waves). Complete-graph edge indexing:
// edge (s->d) has id j = s*63 + (d<s ? d : d-1)  [np.nonzero(~eye) order].
// ---------------------------------------------------------------------------
__global__ __launch_bounds__(512, 2)
void gnn_kernel(const float* __restrict__ x, const float* __restrict__ ea_g,
                const float* __restrict__ W1, const float* __restrict__ a_src1,
                const float* __restrict__ a_dst1, const float* __restrict__ We1,
                const float* __restrict__ a_edge1, const float* __restrict__ b1,
                const float* __restrict__ W2, const float* __restrict__ a_src2,
                const float* __restrict__ a_dst2, const float* __restrict__ We2,
                const float* __restrict__ a_edge2, const float* __restrict__ b2,
                const float* __restrict__ Wg, const float* __restrict__ bg,
                float* __restrict__ embs)
{
  __shared__ float x_s[NN * FF];
  __shared__ float W1_s[FF * PP];
  __shared__ float ea_s[EE];
  __shared__ float hA_s[NN * PP];   // h1 (GAT1 projected), later p2 (GAT2 projected)
  __shared__ float hB_s[NN * PP];   // relu(GAT1 out), later relu(GAT2 out)
  __shared__ float as1_s[NN * 4];
  __shared__ float ad1_s[NN * 4];
  __shared__ float asrc1_s[PP], adst1_s[PP], asrc2_s[PP], adst2_s[PP];
  __shared__ float b1_s[PP], b2_s[PP], Wg_s[PP];
  __shared__ float as2_s[NN], ad2_s[NN];
  __shared__ float coef_s[8 * 64 * 4];
  __shared__ float wed_s[8];
  __shared__ float attn_s[NN];

  const int tid = threadIdx.x;
  const int t = blockIdx.x;
  const int wave = tid >> 6, lane = tid & 63;

  // stage inputs
  for (int i = tid; i < NN * FF; i += 512) x_s[i] = x[t * NN * FF + i];
  for (int i = tid; i < FF * PP; i += 512) W1_s[i] = W1[i];
  for (int i = tid; i < EE; i += 512) ea_s[i] = ea_g[t * EE + i];
  if (tid < PP) {
    asrc1_s[tid] = a_src1[tid]; adst1_s[tid] = a_dst1[tid];
    asrc2_s[tid] = a_src2[tid]; adst2_s[tid] = a_dst2[tid];
    b1_s[tid] = b1[tid]; b2_s[tid] = b2[tid]; Wg_s[tid] = Wg[tid];
  }
  if (tid >= 128 && tid < 132) {   // wedot1[h] = sum_c We1[h,c]*a_edge1[h,c]
    const int h = tid - 128;
    float acc = 0.f;
    for (int c = 0; c < 32; ++c) acc += We1[h * 32 + c] * a_edge1[h * 32 + c];
    wed_s[h] = acc;
  }
  if (tid == 132) {                // wedot2 = dot(We2, a_edge2)
    float acc = 0.f;
    for (int c = 0; c < 128; ++c) acc += We2[c] * a_edge2[c];
    wed_s[4] = acc;
  }
  __syncthreads();

  // h1 = x @ W1  -> hA  (8192 outputs, 16/thread)
  {
    const int c = tid & 127, ib = tid >> 7;
    for (int q = 0; q < 16; ++q) {
      const int i = ib * 16 + q;
      float acc = 0.f;
#pragma unroll
      for (int f = 0; f < FF; ++f) acc += x_s[i * FF + f] * W1_s[f * PP + c];
      hA_s[i * PP + c] = acc;
    }
  }
  __syncthreads();

  // per-node attention dots: as1[i][h], ad1[i][h]
  {
    const int half = tid >> 8;          // 0: src dots, 1: dst dots
    const int tt2 = tid & 255;
    const int i = tt2 >> 2, h = tt2 & 3;
    const float* aw = half ? adst1_s : asrc1_s;
    float acc = 0.f;
    for (int cc = 0; cc < 32; ++cc) {
      const int c = (cc + tid) & 31;    // rotation: LDS bank-conflict-free
      acc += hA_s[i * PP + h * 32 + c] * aw[h * 32 + c];
    }
    if (half) ad1_s[i * 4 + h] = acc; else as1_s[i * 4 + h] = acc;
  }
  __syncthreads();

  // GAT1 aggregation: each wave owns dst d = kk*8+wave; lanes 0..62 = srcs
  for (int kk = 0; kk < 8; ++kk) {
    const int d = kk * 8 + wave;
    {
      float a0, a1, a2, a3;
      if (lane < 63) {
        const int s = lane + (lane >= d ? 1 : 0);
        const int j = s * 63 + (d < s ? d : d - 1);
        const float ev = ea_s[j];
        a0 = as1_s[s * 4 + 0] + ad1_s[d * 4 + 0] + ev * wed_s[0];
        a1 = as1_s[s * 4 + 1] + ad1_s[d * 4 + 1] + ev * wed_s[1];
        a2 = as1_s[s * 4 + 2] + ad1_s[d * 4 + 2] + ev * wed_s[2];
        a3 = as1_s[s * 4 + 3] + ad1_s[d * 4 + 3] + ev * wed_s[3];
        a0 = a0 > 0.f ? a0 : 0.2f * a0;
        a1 = a1 > 0.f ? a1 : 0.2f * a1;
        a2 = a2 > 0.f ? a2 : 0.2f * a2;
        a3 = a3 > 0.f ? a3 : 0.2f * a3;
      } else { a0 = a1 = a2 = a3 = -1e30f; }
      const float m0 = wave_max64(a0), m1 = wave_max64(a1);
      const float m2 = wave_max64(a2), m3 = wave_max64(a3);
      const float p0 = (lane < 63) ? __expf(a0 - m0) : 0.f;
      const float p1 = (lane < 63) ? __expf(a1 - m1) : 0.f;
      const float p2 = (lane < 63) ? __expf(a2 - m2) : 0.f;
      const float p3 = (lane < 63) ? __expf(a3 - m3) : 0.f;
      const float s0 = wave_sum64(p0), s1 = wave_sum64(p1);
      const float s2 = wave_sum64(p2), s3 = wave_sum64(p3);
      float* cw = &coef_s[(wave * 64 + lane) * 4];
      cw[0] = p0 / (s0 + 1e-16f);
      cw[1] = p1 / (s1 + 1e-16f);
      cw[2] = p2 / (s2 + 1e-16f);
      cw[3] = p3 / (s3 + 1e-16f);
    }
    __syncthreads();
    {
      const int c0 = lane * 2;
      const int hh = c0 >> 5;
      float acc0 = 0.f, acc1 = 0.f;
      const float* cf = &coef_s[wave * 64 * 4 + hh];
      for (int s = 0; s < 63; ++s) {
        const int sn = s + (s >= d ? 1 : 0);
        const float cv = cf[s * 4];
        const float2 hv = *(const float2*)&hA_s[sn * PP + c0];
        acc0 += cv * hv.x; acc1 += cv * hv.y;
      }
      hB_s[d * PP + c0]     = fmaxf(acc0 + b1_s[c0], 0.f);
      hB_s[d * PP + c0 + 1] = fmaxf(acc1 + b1_s[c0 + 1], 0.f);
    }
    __syncthreads();
  }

  // p2 = relu(gat1) @ W2 -> hA (reuse; h1 dead).  W2 streamed from L2.
  {
    const int c = tid & 127, ib = tid >> 7;
    float acc[16];
#pragma unroll
    for (int q = 0; q < 16; ++q) acc[q] = 0.f;
    for (int f0 = 0; f0 < 128; f0 += 4) {
      const float w0 = W2[(f0 + 0) * PP + c];
      const float w1 = W2[(f0 + 1) * PP + c];
      const float w2 = W2[(f0 + 2) * PP + c];
      const float w3 = W2[(f0 + 3) * PP + c];
#pragma unroll
      for (int q = 0; q < 16; ++q) {
        const float4 hv = *(const float4*)&hB_s[(ib * 16 + q) * PP + f0];
        acc[q] += hv.x * w0 + hv.y * w1 + hv.z * w2 + hv.w * w3;
      }
    }
#pragma unroll
    for (int q = 0; q < 16; ++q) hA_s[(ib * 16 + q) * PP + c] = acc[q];
  }
  __syncthreads();

  // as2/ad2 node dots
  if (tid < 128) {
    const int i = tid >> 1, sel = tid & 1;
    const float* aw = sel ? adst2_s : asrc2_s;
    float acc = 0.f;
    for (int cc = 0; cc < 128; ++cc) {
      const int c = (cc + tid) & 127;
      acc += hA_s[i * PP + c] * aw[c];
    }
    if (sel) ad2_s[i] = acc; else as2_s[i] = acc;
  }
  __syncthreads();

  // GAT2 aggregation (1 head)
  for (int kk = 0; kk < 8; ++kk) {
    const int d = kk * 8 + wave;
    {
      float a;
      if (lane < 63) {
        const int s = lane + (lane >= d ? 1 : 0);
        const int j = s * 63 + (d < s ? d : d - 1);
        a = as2_s[s] + ad2_s[d] + ea_s[j] * wed_s[4];
        a = a > 0.f ? a : 0.2f * a;
      } else a = -1e30f;
      const float m = wave_max64(a);
      const float p = (lane < 63) ? __expf(a - m) : 0.f;
      const float ssum = wave_sum64(p);
      coef_s[wave * 64 + lane] = p / (ssum + 1e-16f);
    }
    __syncthreads();
    {
      const int c0 = lane * 2;
      float acc0 = 0.f, acc1 = 0.f;
      const float* cf = &coef_s[wave * 64];
      for (int s = 0; s < 63; ++s) {
        const int sn = s + (s >= d ? 1 : 0);
        const float cv = cf[s];
        const float2 hv = *(const float2*)&hA_s[sn * PP + c0];
        acc0 += cv * hv.x; acc1 += cv * hv.y;
      }
      hB_s[d * PP + c0]     = fmaxf(acc0 + b2_s[c0], 0.f);
      hB_s[d * PP + c0 + 1] = fmaxf(acc1 + b2_s[c0 + 1], 0.f);
    }
    __syncthreads();
  }

  // attention pooling (softmax over 64 nodes, wave 0) + max pooling
  if (tid < 64) {
    float acc = 0.f;
    for (int cc = 0; cc < 128; ++cc) {
      const int c = (cc + tid) & 127;
      acc += hB_s[tid * PP + c] * Wg_s[c];
    }
    const float logit = acc + bg[0];
    const float m = wave_max64(logit);
    const float p = __expf(logit - m);
    const float ssum = wave_sum64(p);
    attn_s[tid] = p / ssum;
  }
  __syncthreads();
  if (tid < 128) {
    const int c = tid;
    float acc = 0.f, mx = -1e30f;
    for (int i = 0; i < NN; ++i) {
      const float v = hB_s[i * PP + c];
      acc += attn_s[i] * v;
      mx = fmaxf(mx, v);
    }
    embs[t * 256 + c] = acc;
    embs[t * 256 + 128 + c] = mx;
  }
}

// ---------------------------------------------------------------------------
// Z[t][j] = Wih_f[j,:]·embs[t] + bih_f[j] + bhh_f[j]   (blocks 0..255)
// Zb[j]   = Wih_b[j,:]·embs[255] + bih_b[j] + bhh_b[j] (block 256)
// ---------------------------------------------------------------------------
__global__ __launch_bounds__(512, 2)
void zproj_kernel(const float* __restrict__ embs,
                  const float* __restrict__ Wih_f, const float* __restrict__ bih_f,
                  const float* __restrict__ bhh_f,
                  const float* __restrict__ Wih_b, const float* __restrict__ bih_b,
                  const float* __restrict__ bhh_b,
                  float* __restrict__ Z, float* __restrict__ Zb)
{
  __shared__ float e_s[256];
  const int t = blockIdx.x;
  const int j = threadIdx.x;
  const bool bwd = (t == TT);
  const int tsrc = bwd ? (TT - 1) : t;
  if (j < 256) e_s[j] = embs[tsrc * 256 + j];
  __syncthreads();
  const float* W = bwd ? Wih_b : Wih_f;
  float acc = bwd ? (bih_b[j] + bhh_b[j]) : (bih_f[j] + bhh_f[j]);
  const float4* Wr = (const float4*)(W + j * 256);
  const float4* er = (const float4*)e_s;
#pragma unroll 8
  for (int k = 0; k < 64; ++k) {
    const float4 w = Wr[k];
    const float4 e = er[k];
    acc += w.x * e.x + w.y * e.y + w.z * e.z + w.w * e.w;
  }
  if (bwd) Zb[j] = acc; else Z[t * 512 + j] = acc;
}

// ---------------------------------------------------------------------------
// Forward LSTM recurrence (256 steps, single block, Whh rows in VGPRs),
// single-step backward LSTM (elementwise on Zb since h=c=0), final head.
// ---------------------------------------------------------------------------
__global__ __launch_bounds__(512, 2)
void lstm_kernel(const float* __restrict__ Z, const float* __restrict__ Zb,
                 const float* __restrict__ Whh_f,
                 const float* __restrict__ Wo, const float* __restrict__ bo,
                 float* __restrict__ out)
{
  __shared__ float h_s[128];
  __shared__ float g_s[512];
  __shared__ float hb_s[128];
  __shared__ float red_s[8];
  const int j = threadIdx.x;

  float w[128];
  {
    const float4* Wr = (const float4*)(Whh_f + j * 128);
#pragma unroll
    for (int k = 0; k < 32; ++k) {
      const float4 v = Wr[k];
      w[4 * k + 0] = v.x; w[4 * k + 1] = v.y; w[4 * k + 2] = v.z; w[4 * k + 3] = v.w;
    }
  }
  float c = 0.f;
  if (j < 128) h_s[j] = 0.f;
  __syncthreads();

  float zcur = Z[j];
  for (int t = 0; t < TT; ++t) {
    const float znext = (t < TT - 1) ? Z[(t + 1) * 512 + j] : 0.f;  // prefetch
    float acc = zcur;
    const float4* hr = (const float4*)h_s;
#pragma unroll
    for (int k = 0; k < 32; ++k) {
      const float4 h4 = hr[k];
      acc += h4.x * w[4 * k] + h4.y * w[4 * k + 1] + h4.z * w[4 * k + 2] + h4.w * w[4 * k + 3];
    }
    g_s[j] = acc;
    __syncthreads();
    if (j < 128) {
      const float gi = g_s[j], gf = g_s[128 + j], gg = g_s[256 + j], go = g_s[384 + j];
      c = sigm(gf) * c + sigm(gi) * tanh_fast(gg);
      h_s[j] = sigm(go) * tanh_fast(c);
    }
    __syncthreads();
    zcur = znext;
  }

  // backward LSTM, first step only (h=c=0): elementwise on Zb
  if (j < 128) {
    const float gi = Zb[j], gg = Zb[256 + j], go = Zb[384 + j];
    const float cb = sigm(gi) * tanh_fast(gg);
    hb_s[j] = sigm(go) * tanh_fast(cb);
  }
  __syncthreads();

  // out = sigmoid(concat(h_f, h_b) · Wo + bo)
  float v = 0.f;
  if (j < 128) v = h_s[j] * Wo[j];
  else if (j < 256) v = hb_s[j - 128] * Wo[j];
  v = wave_sum64(v);
  if ((j & 63) == 0) red_s[j >> 6] = v;
  __syncthreads();
  if (j == 0) {
    float s = bo[0];
#pragma unroll
    for (int k = 0; k < 8; ++k) s += red_s[k];
    out[0] = 1.f / (1.f + __expf(-s));
  }
}

extern "C" void kernel_launch(void* const* d_in, const int* in_sizes, int n_in,
                              void* d_out, int out_size, void* d_ws, size_t ws_size,
                              hipStream_t stream) {
  const float* x       = (const float*)d_in[0];
  // d_in[1] = edge_index (int32) — complete digraph, indexed analytically
  const float* ea      = (const float*)d_in[2];
  const float* W1      = (const float*)d_in[3];
  const float* a_src1  = (const float*)d_in[4];
  const float* a_dst1  = (const float*)d_in[5];
  const float* We1     = (const float*)d_in[6];
  const float* a_edge1 = (const float*)d_in[7];
  const float* b1      = (const float*)d_in[8];
  const float* W2      = (const float*)d_in[9];
  const float* a_src2  = (const float*)d_in[10];
  const float* a_dst2  = (const float*)d_in[11];
  const float* We2     = (const float*)d_in[12];
  const float* a_edge2 = (const float*)d_in[13];
  const float* b2      = (const float*)d_in[14];
  const float* Wg      = (const float*)d_in[15];
  const float* bg      = (const float*)d_in[16];
  const float* Wih_f   = (const float*)d_in[17];
  const float* Whh_f   = (const float*)d_in[18];
  const float* bih_f   = (const float*)d_in[19];
  const float* bhh_f   = (const float*)d_in[20];
  const float* Wih_b   = (const float*)d_in[21];
  // d_in[22] = Whh_b — unused: backward LSTM contributes only its first step (h=0)
  const float* bih_b   = (const float*)d_in[23];
  const float* bhh_b   = (const float*)d_in[24];
  const float* Wo      = (const float*)d_in[25];
  const float* bo      = (const float*)d_in[26];
  float* out = (float*)d_out;

  float* embs = (float*)d_ws;            // 256*256 floats
  float* Z    = embs + 256 * 256;        // 256*512 floats
  float* Zb   = Z + 256 * 512;           // 512 floats

  gnn_kernel<<<256, 512, 0, stream>>>(x, ea, W1, a_src1, a_dst1, We1, a_edge1, b1,
                                      W2, a_src2, a_dst2, We2, a_edge2, b2, Wg, bg, embs);
  zproj_kernel<<<257, 512, 0, stream>>>(embs, Wih_f, bih_f, bhh_f, Wih_b, bih_b, bhh_b, Z, Zb);
  lstm_kernel<<<1, 512, 0, stream>>>(Z, Zb, Whh_f, Wo, bo, out);
}